// Round 6
// baseline (571.773 us; speedup 1.0000x reference)
//
#include <hip/hip_runtime.h>

#define DIM 128
#define NCB 8
#define KSZ 2048
#define BATCH 16
#define TOK 2048
#define NTOK (BATCH * TOK)            // 32768
#define NELEM (BATCH * DIM * TOK)     // 4194304
#define T_TILE 64                     // tokens per block
#define NTHR 512                      // 8 waves; wave-pair shares 16 tokens,
                                      // each wave sweeps half the codebook
#define CHUNK 32                      // codes per chunk (per half)
#define HCHUNKS 32                    // chunks per half (1024 / 32)

typedef float f32x4 __attribute__((ext_vector_type(4)));
typedef short s16x8 __attribute__((ext_vector_type(8)));

__device__ __forceinline__ unsigned short f2bf(float f) {
    unsigned u = __float_as_uint(f);
    u = (u + 0x7FFFu + ((u >> 16) & 1u)) >> 16;   // RNE, finite inputs only
    return (unsigned short)u;
}
__device__ __forceinline__ float bf2f(unsigned short h) {
    return __uint_as_float(((unsigned)h) << 16);
}

// ---------------------------------------------------------------------------
// prep: codebooks -> bf16 hi plane only
// ---------------------------------------------------------------------------
__global__ void rvq_prep_hi(const float* __restrict__ cbs,
                            unsigned short* __restrict__ ch) {
    int i = blockIdx.x * 256 + threadIdx.x;
    ch[i] = f2bf(cbs[i]);
}

// ---------------------------------------------------------------------------
// exact fp32 cnorm + zero loss accumulator
// ---------------------------------------------------------------------------
__global__ void rvq_cnorm(const float* __restrict__ cbs,
                          float* __restrict__ cnorm,
                          float* __restrict__ loss_acc) {
    if (blockIdx.x == 0 && threadIdx.x == 0) *loss_acc = 0.0f;
    int k = blockIdx.x * 256 + threadIdx.x;
    const float4* row = (const float4*)(cbs + (size_t)k * DIM);
    float s = 0.0f;
#pragma unroll
    for (int i = 0; i < DIM / 4; ++i) {
        float4 v = row[i];
        s += v.x * v.x + v.y * v.y + v.z * v.z + v.w * v.w;
    }
    cnorm[k] = s;
}

// ---------------------------------------------------------------------------
// fused RVQ. 8 waves/block, T_TILE=64, grid=512, LDS 74.2 KB ->
// 2 blocks/CU = 16 waves/CU (2x TLP vs the 8-waves/CU of all passing rounds).
// Wave wv: wg=wv>>1 owns tokens wg*16..+15 (shared with its pair),
// h2=wv&1 sweeps codebook half h2 in 32 chunks of 32 codes.
// Residual exact fp32 in res_lds (round-0/1/2 numerics). Approx scores:
// split-bf16 MFMA (hh+lh = r * c_hi); per-lane exact top-2 per mod-16 class
// per half (pool 64/token, per-class best guaranteed); 8-thr/token merge ->
// top-4 -> round-2-VERBATIM exact fp32 rescore (rn-inclusive dist: matches
// reference fp32 rounding at near-ties; rn-less ordering broke rounds 4/5).
// ---------------------------------------------------------------------------
__global__ __launch_bounds__(NTHR, 4) void rvq_fused(
        const float* __restrict__ x,            // (B, D, T)
        const float* __restrict__ cbs,          // (NCB, KSZ, DIM) fp32
        const unsigned short* __restrict__ ch,  // bf16 hi
        const float* __restrict__ cng,          // (NCB*KSZ) exact cnorm
        float* __restrict__ out,                // (B, D, T)
        float* __restrict__ codes,              // (B, NCB, T) as float
        float* __restrict__ loss_acc) {
    __shared__ float res_lds[T_TILE][DIM + 2];     // 33280 B
    __shared__ unsigned short Bbuf[2][4096];       // 16384 B (8 KB per half)
    __shared__ float mv1[T_TILE * 32];             // 8192 B
    __shared__ float mv2[T_TILE * 32];             // 8192 B
    __shared__ unsigned short mi1[T_TILE * 32];    // 4096 B
    __shared__ unsigned short mi2[T_TILE * 32];    // 4096 B
    __shared__ unsigned short best4s[T_TILE][4];   // 512 B  => 74752 B

    const int tid   = threadIdx.x;
    const int lane  = tid & 63;
    const int wv    = __builtin_amdgcn_readfirstlane(tid >> 6);  // 0..7
    const int col16 = lane & 15;
    const int quad  = lane >> 4;
    const int h2    = wv & 1;          // codebook half this wave sweeps
    const int wg    = wv >> 1;         // token group (0..3)

    const int token0 = blockIdx.x * T_TILE;
    const int b      = token0 >> 11;
    const int t_in_b = token0 & (TOK - 1);

    // ---- init: x[b][d][t0..] -> res_lds[t][d] ----
    {
        const float* xb = x + (size_t)b * DIM * TOK + t_in_b;
#pragma unroll
        for (int it = 0; it < 4; ++it) {
            int idx = it * NTHR + tid;           // 0..2047
            int d  = idx >> 4;
            int t4 = (idx & 15) * 4;
            float4 v = *(const float4*)(xb + (size_t)d * TOK + t4);
            res_lds[t4 + 0][d] = v.x;
            res_lds[t4 + 1][d] = v.y;
            res_lds[t4 + 2][d] = v.z;
            res_lds[t4 + 3][d] = v.w;
        }
    }
    __syncthreads();

    float my_loss = 0.0f;

// wave wv stages frags f = wg*2, wg*2+1 of its half's chunk
// (f = rowgrp*4 + dimchunk; wg 0..3 covers 2 rowgroups x 4 dimchunks)
#define STAGE_LOAD(cc)                                                         \
    {                                                                          \
        const int _f0 = wg * 2, _f1 = wg * 2 + 1;                              \
        stg0 = *(const s16x8*)(ch_s +                                          \
            ((size_t)(h2 * 1024 + (cc) * CHUNK + (_f0 >> 2) * 16 + col16)) * DIM + \
            ((_f0 & 3) * 32 + quad * 8));                                      \
        stg1 = *(const s16x8*)(ch_s +                                          \
            ((size_t)(h2 * 1024 + (cc) * CHUNK + (_f1 >> 2) * 16 + col16)) * DIM + \
            ((_f1 & 3) * 32 + quad * 8));                                      \
    }

#define STAGE_WRITE()                                                          \
    {                                                                          \
        *(s16x8*)&Bbuf[h2][(wg * 2 + 0) * 512 + lane * 8] = stg0;              \
        *(s16x8*)&Bbuf[h2][(wg * 2 + 1) * 512 + lane * 8] = stg1;              \
    }

// 16 MFMA over 16 tokens x 32 codes (2 row-groups); insert BOTH scores into
// the per-lane top-2 (exact top-2 of the (token, mod-16 class, half) slice).
#define COMPUTE_FOLD(cc)                                                       \
    {                                                                          \
        f32x4 a0 = (f32x4){0.f, 0.f, 0.f, 0.f};                                \
        f32x4 a1 = a0;                                                         \
        _Pragma("unroll")                                                      \
        for (int dc = 0; dc < 4; ++dc) {                                       \
            s16x8 b0 = *(const s16x8*)&Bbuf[h2][(0 + dc) * 512 + lane * 8];    \
            s16x8 b1 = *(const s16x8*)&Bbuf[h2][(4 + dc) * 512 + lane * 8];    \
            a0 = __builtin_amdgcn_mfma_f32_16x16x32_bf16(ah[dc], b0, a0, 0, 0, 0); \
            a0 = __builtin_amdgcn_mfma_f32_16x16x32_bf16(al[dc], b0, a0, 0, 0, 0); \
            a1 = __builtin_amdgcn_mfma_f32_16x16x32_bf16(ah[dc], b1, a1, 0, 0, 0); \
            a1 = __builtin_amdgcn_mfma_f32_16x16x32_bf16(al[dc], b1, a1, 0, 0, 0); \
        }                                                                      \
        const int _ib0 = h2 * 1024 + (cc) * CHUNK + col16;                     \
        const float _cn0 = cn_s[_ib0], _cn1 = cn_s[_ib0 + 16];                 \
        _Pragma("unroll")                                                      \
        for (int r = 0; r < 4; ++r) {                                          \
            float p0 = fmaf(-2.0f, a0[r], _cn0);                               \
            float p1 = fmaf(-2.0f, a1[r], _cn1);                               \
            bool q1 = p0 < v1[r];                                              \
            bool q2 = p0 < v2[r];                                              \
            v2[r] = q1 ? v1[r] : (q2 ? p0 : v2[r]);                            \
            i2[r] = q1 ? i1[r] : (q2 ? _ib0 : i2[r]);                          \
            v1[r] = q1 ? p0 : v1[r];                                           \
            i1[r] = q1 ? _ib0 : i1[r];                                         \
            bool w1 = p1 < v1[r];                                              \
            bool w2 = p1 < v2[r];                                              \
            v2[r] = w1 ? v1[r] : (w2 ? p1 : v2[r]);                            \
            i2[r] = w1 ? i1[r] : (w2 ? (_ib0 + 16) : i2[r]);                   \
            v1[r] = w1 ? p1 : v1[r];                                           \
            i1[r] = w1 ? (_ib0 + 16) : i1[r];                                  \
        }                                                                      \
    }

#pragma unroll 1
    for (int s = 0; s < NCB; ++s) {
        const unsigned short* __restrict__ ch_s = ch  + (size_t)s * KSZ * DIM;
        const float* __restrict__ cb_s = cbs + (size_t)s * KSZ * DIM;
        const float* __restrict__ cn_s = cng + (size_t)s * KSZ;

        s16x8 stg0, stg1;

        // issue chunk-0 loads, then derive A-frags while they fly
        STAGE_LOAD(0);

        // ---- A fragments (hi+lo) from the exact fp32 LDS residual ----
        s16x8 ah[4], al[4];
#pragma unroll
        for (int dc = 0; dc < 4; ++dc) {
            int t  = wg * 16 + col16;
            int d0 = dc * 32 + quad * 8;
            float4 u = *(const float4*)&res_lds[t][d0];
            float4 w = *(const float4*)&res_lds[t][d0 + 4];
            float e[8] = {u.x, u.y, u.z, u.w, w.x, w.y, w.z, w.w};
            s16x8 hv, lv;
#pragma unroll
            for (int j = 0; j < 8; ++j) {
                unsigned short hb = f2bf(e[j]);
                hv[j] = (short)hb;
                lv[j] = (short)f2bf(e[j] - bf2f(hb));
            }
            ah[dc] = hv; al[dc] = lv;
        }

        float v1[4], v2[4]; int i1[4], i2[4];
#pragma unroll
        for (int r = 0; r < 4; ++r) {
            v1[r] = 3.4e38f; v2[r] = 3.4e38f; i1[r] = 0; i2[r] = 0;
        }

        // ---- chunk sweep over this wave's half ----
        STAGE_WRITE(); __syncthreads();
#pragma unroll 1
        for (int cc = 0; cc < HCHUNKS - 1; ++cc) {
            STAGE_LOAD(cc + 1);          // in flight during COMPUTE
            COMPUTE_FOLD(cc);
            __syncthreads();             // everyone done reading Bbuf
            STAGE_WRITE();
            __syncthreads();             // staging visible
        }
        COMPUTE_FOLD(HCHUNKS - 1);

        // ---- publish per-lane top-2 (token rows of width 32) ----
#pragma unroll
        for (int r = 0; r < 4; ++r) {
            int t = wg * 16 + quad * 4 + r;
            int o = t * 32 + h2 * 16 + col16;
            mv1[o] = v1[r];
            mi1[o] = (unsigned short)i1[r];
            mv2[o] = v2[r];
            mi2[o] = (unsigned short)i2[r];
        }
        __syncthreads();

        // ---- merge 64 candidates -> top-4: 8 thr/token, 8 cands each ----
        {
            const int mt = tid >> 3;      // 0..63
            const int c8 = tid & 7;
            float bv[4] = {3.4e38f, 3.4e38f, 3.4e38f, 3.4e38f};
            int   bi[4] = {0x7FFFFFFF, 0x7FFFFFFF, 0x7FFFFFFF, 0x7FFFFFFF};
            const float* MV = (c8 & 4) ? mv2 : mv1;
            const unsigned short* MI = (c8 & 4) ? mi2 : mi1;
            const int base = mt * 32 + (c8 & 3) * 8;
            const float4 va = *(const float4*)&MV[base];
            const float4 vb = *(const float4*)&MV[base + 4];
            const s16x8  qi = *(const s16x8*)&MI[base];
            float vv[8] = {va.x, va.y, va.z, va.w, vb.x, vb.y, vb.z, vb.w};
#pragma unroll
            for (int c = 0; c < 8; ++c) {
                float v = vv[c]; int i = (int)(unsigned short)qi[c];
#pragma unroll
                for (int j = 0; j < 4; ++j) {
                    if (v < bv[j] || (v == bv[j] && i < bi[j])) {
                        float tv = bv[j]; bv[j] = v; v = tv;
                        int   ti = bi[j]; bi[j] = i; i = ti;
                    }
                }
            }
#pragma unroll
            for (int mk = 1; mk <= 4; mk <<= 1) {
                float ov[4]; int oi[4];
#pragma unroll
                for (int j = 0; j < 4; ++j) {
                    ov[j] = __shfl_xor(bv[j], mk, 64);
                    oi[j] = __shfl_xor(bi[j], mk, 64);
                }
#pragma unroll
                for (int c = 0; c < 4; ++c) {
                    float v = ov[c]; int i = oi[c];
#pragma unroll
                    for (int j = 0; j < 4; ++j) {
                        if (v < bv[j] || (v == bv[j] && i < bi[j])) {
                            float tv = bv[j]; bv[j] = v; v = tv;
                            int   ti = bi[j]; bi[j] = i; i = ti;
                        }
                    }
                }
            }
            if (c8 < 4) best4s[mt][c8] = (unsigned short)bi[c8];
        }
        __syncthreads();

        // ---- exact fp32 rescore (round-2 VERBATIM formula, rn-inclusive):
        //      8 thr/token; groups c8<4 / c8>=4 redundantly rescore cands 0-3
        {
            const int t  = tid >> 3;
            const int c8 = tid & 7;
            const int cand = best4s[t][c8 & 3];
            const float* crow = cb_s + (size_t)cand * DIM;
            float n0 = 0, n1 = 0, n2 = 0, n3 = 0;
            float a0 = 0, a1 = 0, a2 = 0, a3 = 0;
#pragma unroll 8
            for (int d4 = 0; d4 < DIM / 4; ++d4) {
                float4 r4 = *(const float4*)&res_lds[t][d4 * 4];
                float4 q4 = *(const float4*)&crow[d4 * 4];
                n0 = fmaf(r4.x, r4.x, n0); n1 = fmaf(r4.y, r4.y, n1);
                n2 = fmaf(r4.z, r4.z, n2); n3 = fmaf(r4.w, r4.w, n3);
                a0 = fmaf(r4.x, q4.x, a0); a1 = fmaf(r4.y, q4.y, a1);
                a2 = fmaf(r4.z, q4.z, a2); a3 = fmaf(r4.w, q4.w, a3);
            }
            float rn  = (n0 + n1) + (n2 + n3);
            float dot = (a0 + a1) + (a2 + a3);
            float dist = fmaf(-2.0f, dot, rn) + cn_s[cand];
            int best = cand;
#pragma unroll
            for (int mk = 1; mk <= 2; mk <<= 1) {
                float od = __shfl_xor(dist, mk, 64);
                int   oi = __shfl_xor(best, mk, 64);
                if (od < dist || (od == dist && oi < best)) {
                    dist = od; best = oi;
                }
            }
            if (c8 == 0)
                codes[(size_t)b * (NCB * TOK) + (size_t)s * TOK + t_in_b + t] =
                    (float)best;
            // update my 16-dim slice of the token's residual + loss partial
            const float* qrow = cb_s + (size_t)best * DIM;
            float lp = 0.0f;
#pragma unroll
            for (int k4 = 0; k4 < 4; ++k4) {
                int d = c8 * 16 + k4 * 4;
                float4 r4 = *(const float4*)&res_lds[t][d];
                float4 q4 = *(const float4*)&qrow[d];
                float4 nr;
                nr.x = r4.x - q4.x; nr.y = r4.y - q4.y;
                nr.z = r4.z - q4.z; nr.w = r4.w - q4.w;
                *(float4*)&res_lds[t][d] = nr;
                lp += nr.x * nr.x + nr.y * nr.y + nr.z * nr.z + nr.w * nr.w;
            }
            my_loss += lp;
        }
        __syncthreads();
    }

    // ---- epilogue: out[b][d][t] = x - residual ----
    {
        const float* xb = x + (size_t)b * DIM * TOK + t_in_b;
        float* ob = out + (size_t)b * DIM * TOK + t_in_b;
#pragma unroll
        for (int it = 0; it < 4; ++it) {
            int idx = it * NTHR + tid;
            int d  = idx >> 4;
            int t4 = (idx & 15) * 4;
            float4 v = *(const float4*)(xb + (size_t)d * TOK + t4);
            float4 o;
            o.x = v.x - res_lds[t4 + 0][d];
            o.y = v.y - res_lds[t4 + 1][d];
            o.z = v.z - res_lds[t4 + 2][d];
            o.w = v.w - res_lds[t4 + 3][d];
            *(float4*)(ob + (size_t)d * TOK + t4) = o;
        }
    }

    // ---- loss reduction ----
#pragma unroll
    for (int off = 32; off > 0; off >>= 1)
        my_loss += __shfl_down(my_loss, off, 64);
    if (lane == 0) atomicAdd(loss_acc, my_loss);
}

// ---------------------------------------------------------------------------
__global__ void rvq_loss_fin(const float* __restrict__ loss_acc,
                             float* __restrict__ loss_out) {
    *loss_out = *loss_acc * (1.0f / (float)NELEM);
}

// ---------------------------------------------------------------------------
extern "C" void kernel_launch(void* const* d_in, const int* in_sizes, int n_in,
                              void* d_out, int out_size, void* d_ws, size_t ws_size,
                              hipStream_t stream) {
    const float* x   = (const float*)d_in[0];   // (B, D, T)
    const float* cbs = (const float*)d_in[1];   // (NCB, KSZ, DIM)

    float* out      = (float*)d_out;
    float* codes    = out + NELEM;
    float* loss_out = out + NELEM + (size_t)BATCH * NCB * TOK;

    float* wsf      = (float*)d_ws;
    float* loss_acc = wsf;
    unsigned short* ch = (unsigned short*)(wsf + 256);
    float* cng = (float*)(ch + (size_t)NCB * KSZ * DIM);

    hipLaunchKernelGGL(rvq_prep_hi, dim3((NCB * KSZ * DIM) / 256), dim3(256),
                       0, stream, cbs, ch);
    hipLaunchKernelGGL(rvq_cnorm, dim3((NCB * KSZ) / 256), dim3(256), 0, stream,
                       cbs, cng, loss_acc);
    hipLaunchKernelGGL(rvq_fused, dim3(NTOK / T_TILE), dim3(NTHR), 0, stream,
                       x, cbs, ch, cng, out, codes, loss_acc);
    hipLaunchKernelGGL(rvq_loss_fin, dim3(1), dim3(1), 0, stream,
                       loss_acc, loss_out);
}